// Round 4
// baseline (1017.389 us; speedup 1.0000x reference)
//
#include <hip/hip_runtime.h>

typedef _Float16 half2_t __attribute__((ext_vector_type(2)));

constexpr int D = 256;
constexpr int NUTT = 64;
constexpr int L = 512;
constexpr int G = 768;           // 3*D

__device__ __forceinline__ half2_t u2h(unsigned int u) {
  return __builtin_bit_cast(half2_t, u);
}

__device__ __forceinline__ float fdot2(half2_t a, half2_t b, float c) {
#if defined(__has_builtin)
#if __has_builtin(__builtin_amdgcn_fdot2)
  return __builtin_amdgcn_fdot2(a, b, c, false);
#else
  return c + (float)a.x * (float)b.x + (float)a.y * (float)b.y;
#endif
#else
  return c + (float)a.x * (float)b.x + (float)a.y * (float)b.y;
#endif
}

// LDS-only barrier: orders ds_* ops across the workgroup WITHOUT draining
// vmcnt — global prefetch loads / wo stores stay in flight across steps.
__device__ __forceinline__ void lds_barrier() {
  asm volatile("s_waitcnt lgkmcnt(0)\n\ts_barrier" ::: "memory");
}

__device__ __forceinline__ float sigm(float x) {
  return 1.0f / (1.0f + __expf(-x));
}
__device__ __forceinline__ float tanh_f(float x) {
  float ax = fabsf(x);
  float e = __expf(-2.0f * ax);
  float r = (1.0f - e) / (1.0f + e);
  return copysignf(r, x);
}

// ---------------------------------------------------------------------------
// Kernel B: gx[m][g] = embed[tokens[m]][:] . Wih[g][:] + bih[g]
// m = b*L + t  (M = 32768), g in [0,768).  Tiled fp32 GEMM, BM=64 BN=128 BK=32
// ---------------------------------------------------------------------------
__global__ __launch_bounds__(256) void gx_gemm(
    const int* __restrict__ tokens, const float* __restrict__ embed,
    const float* __restrict__ Wih, const float* __restrict__ bih,
    float* __restrict__ gx) {
  __shared__ float As[64][33];
  __shared__ float Bs[32][129];
  __shared__ int toks[64];

  const int tid = threadIdx.x;
  const int m0 = blockIdx.x * 64;
  const int n0 = blockIdx.y * 128;
  if (tid < 64) toks[tid] = tokens[m0 + tid];
  __syncthreads();

  const int ty = tid >> 4;   // 0..15 : row group (4 rows each)
  const int tx = tid & 15;   // 0..15 : col base (cols tx + 16*cc)
  float acc[4][8] = {};

  for (int k0 = 0; k0 < 256; k0 += 32) {
    // stage A (embedding gather rows)
    {
      const int i = tid >> 2;            // 0..63
      const int kq = (tid & 3) * 4;      // 0,4,8,12
      const float* src = embed + (size_t)toks[i] * D + k0;
      float4 v0 = *(const float4*)(src + kq);
      float4 v1 = *(const float4*)(src + kq + 16);
      As[i][kq + 0] = v0.x; As[i][kq + 1] = v0.y;
      As[i][kq + 2] = v0.z; As[i][kq + 3] = v0.w;
      As[i][kq + 16] = v1.x; As[i][kq + 17] = v1.y;
      As[i][kq + 18] = v1.z; As[i][kq + 19] = v1.w;
    }
    // stage B (weights, transposed into [k][g])
    {
      const int goff = tid >> 3;         // 0..31
      const int kq = (tid & 7) * 4;      // 0..28
      for (int gp = 0; gp < 128; gp += 32) {
        const float* src = Wih + (size_t)(n0 + goff + gp) * D + k0 + kq;
        float4 v = *(const float4*)src;
        Bs[kq + 0][goff + gp] = v.x;
        Bs[kq + 1][goff + gp] = v.y;
        Bs[kq + 2][goff + gp] = v.z;
        Bs[kq + 3][goff + gp] = v.w;
      }
    }
    __syncthreads();
    const int r0 = ty * 4;
#pragma unroll 4
    for (int k = 0; k < 32; ++k) {
      float a0 = As[r0 + 0][k], a1 = As[r0 + 1][k];
      float a2 = As[r0 + 2][k], a3 = As[r0 + 3][k];
#pragma unroll
      for (int cc = 0; cc < 8; ++cc) {
        float bv = Bs[k][tx + 16 * cc];
        acc[0][cc] = fmaf(a0, bv, acc[0][cc]);
        acc[1][cc] = fmaf(a1, bv, acc[1][cc]);
        acc[2][cc] = fmaf(a2, bv, acc[2][cc]);
        acc[3][cc] = fmaf(a3, bv, acc[3][cc]);
      }
    }
    __syncthreads();
  }
#pragma unroll
  for (int rr = 0; rr < 4; ++rr) {
    float* dst = gx + (size_t)(m0 + ty * 4 + rr) * G + n0;
#pragma unroll
    for (int cc = 0; cc < 8; ++cc) {
      int c = tx + 16 * cc;
      dst[c] = acc[rr][cc] + bih[n0 + c];
    }
  }
}

// ---------------------------------------------------------------------------
// Kernel C: persistent word-GRU scan. 64 WGs x 512 threads (8 waves, 2/SIMD).
// Thread t: d = t>>1 (state dim), kh = t&1 (K half) — the two K-half partners
// of a given d are ADJACENT LANES of the same wave.
//   - 3 x 64 half2 weight rows in VGPRs per thread (r,z,n gate rows, K-half)
//   - partial sums combined with __shfl_xor(.,1): in-wave, no barrier
//   - update computed redundantly by both partners (no divergence phase)
//   - h (f16) double-buffered in LDS -> ONE LDS-only barrier per step
//   - h broadcast reads: 2 distinct addrs/wave per ds_read_b128 (free, m136)
// ---------------------------------------------------------------------------
__global__ __launch_bounds__(512, 2) void gru_scan_word(
    const float* __restrict__ gx,    // [NUTT][L][G] (includes b_ih)
    const float* __restrict__ Whh,   // [G][D]
    const float* __restrict__ bhh,   // [G]
    float* __restrict__ wo) {        // [NUTT][L][D]
  __shared__ uint4 h4[2][32];        // f16 h, double-buffered (512 B x2)

  const int t = threadIdx.x;
  const int b = blockIdx.x;
  const int d = t >> 1;              // 0..255
  const int kh = t & 1;              // 0: k<128, 1: k>=128

  // --- load this thread's 3 half-rows into VGPRs (f16) ---
  half2_t wr[64], wz[64], wn[64];
  {
    const float* rowR = Whh + (size_t)d * D + kh * 128;
    const float* rowZ = Whh + (size_t)(D + d) * D + kh * 128;
    const float* rowN = Whh + (size_t)(2 * D + d) * D + kh * 128;
#pragma unroll
    for (int c = 0; c < 32; ++c) {
      float4 v = *(const float4*)(rowR + 4 * c);
      wr[2 * c]     = half2_t{(_Float16)v.x, (_Float16)v.y};
      wr[2 * c + 1] = half2_t{(_Float16)v.z, (_Float16)v.w};
    }
#pragma unroll
    for (int c = 0; c < 32; ++c) {
      float4 v = *(const float4*)(rowZ + 4 * c);
      wz[2 * c]     = half2_t{(_Float16)v.x, (_Float16)v.y};
      wz[2 * c + 1] = half2_t{(_Float16)v.z, (_Float16)v.w};
    }
#pragma unroll
    for (int c = 0; c < 32; ++c) {
      float4 v = *(const float4*)(rowN + 4 * c);
      wn[2 * c]     = half2_t{(_Float16)v.x, (_Float16)v.y};
      wn[2 * c + 1] = half2_t{(_Float16)v.z, (_Float16)v.w};
    }
  }

  const float bR = bhh[d];
  const float bZ = bhh[D + d];
  const float bN = bhh[2 * D + d];
  const float* gxb = gx + (size_t)b * L * G;
  float gr = gxb[d];
  float gz = gxb[D + d];
  float gn = gxb[2 * D + d];
  if (t < 32) h4[0][t] = uint4{0u, 0u, 0u, 0u};
  float hprev = 0.0f;
  float* wob = wo + (size_t)b * L * D;
  __syncthreads();

  for (int ts = 0; ts < L; ++ts) {
    const int cur = ts & 1;
    const uint4* hv = &h4[cur][kh * 16];
    float aR = 0.0f, aZ = 0.0f, aN = 0.0f;
#pragma unroll
    for (int c = 0; c < 16; ++c) {   // 1 b128 2-addr broadcast -> 12 dot2
      uint4 v = hv[c];
      half2_t h0 = u2h(v.x), h1 = u2h(v.y), h2 = u2h(v.z), h3 = u2h(v.w);
      aR = fdot2(wr[4 * c + 0], h0, aR);
      aZ = fdot2(wz[4 * c + 0], h0, aZ);
      aN = fdot2(wn[4 * c + 0], h0, aN);
      aR = fdot2(wr[4 * c + 1], h1, aR);
      aZ = fdot2(wz[4 * c + 1], h1, aZ);
      aN = fdot2(wn[4 * c + 1], h1, aN);
      aR = fdot2(wr[4 * c + 2], h2, aR);
      aZ = fdot2(wz[4 * c + 2], h2, aZ);
      aN = fdot2(wn[4 * c + 2], h2, aN);
      aR = fdot2(wr[4 * c + 3], h3, aR);
      aZ = fdot2(wz[4 * c + 3], h3, aZ);
      aN = fdot2(wn[4 * c + 3], h3, aN);
    }
    // combine K-half partials with the adjacent lane (same wave, no barrier)
    aR += __shfl_xor(aR, 1, 64);
    aZ += __shfl_xor(aZ, 1, 64);
    aN += __shfl_xor(aN, 1, 64);

    // redundant update on both partners (no divergent serial phase)
    float r = sigm(gr + aR + bR);
    float z = sigm(gz + aZ + bZ);
    float n = tanh_f(gn + r * (aN + bN));
    float hn = fmaf(z, hprev - n, n);          // (1-z)*n + z*h
    hprev = hn;
    if (kh == 0) {
      reinterpret_cast<_Float16*>(h4[cur ^ 1])[d] = (_Float16)hn;
      wob[(size_t)ts * D + d] = hn;
    }
    // prefetch next step's gx (covered by the whole next step's latency)
    const int tn = (ts + 1 < L) ? ts + 1 : ts;
    const float* gxn = gxb + (size_t)tn * G;
    gr = gxn[d]; gz = gxn[D + d]; gn = gxn[2 * D + d];
    lds_barrier();
  }
}

// ---------------------------------------------------------------------------
// Kernel D: attention pool over word_out -> utt[64][256]
// ---------------------------------------------------------------------------
__global__ __launch_bounds__(256) void attn_pool_word(
    const float* __restrict__ wo, const float* __restrict__ uaw,
    float* __restrict__ utt) {
  __shared__ float wsh[D];
  __shared__ float lg[L];
  __shared__ float red[8];
  const int tid = threadIdx.x, b = blockIdx.x;
  wsh[tid] = uaw[tid];
  __syncthreads();

  const int wid = tid >> 6, lane = tid & 63;
  const float* base = wo + (size_t)b * L * D;
  for (int t = wid; t < L; t += 4) {
    const float* row = base + (size_t)t * D;
    float p = 0.0f;
#pragma unroll
    for (int j = 0; j < 4; ++j) p = fmaf(row[lane + 64 * j], wsh[lane + 64 * j], p);
#pragma unroll
    for (int off = 32; off; off >>= 1) p += __shfl_down(p, off);
    if (lane == 0) lg[t] = p;                  // ua_b cancels in softmax
  }
  __syncthreads();

  float m = fmaxf(lg[tid], lg[tid + 256]);
#pragma unroll
  for (int off = 32; off; off >>= 1) m = fmaxf(m, __shfl_down(m, off));
  if (lane == 0) red[wid] = m;
  __syncthreads();
  m = fmaxf(fmaxf(red[0], red[1]), fmaxf(red[2], red[3]));

  float e0 = __expf(lg[tid] - m), e1 = __expf(lg[tid + 256] - m);
  float s = e0 + e1;
#pragma unroll
  for (int off = 32; off; off >>= 1) s += __shfl_down(s, off);
  if (lane == 0) red[4 + wid] = s;
  __syncthreads();
  s = red[4] + red[5] + red[6] + red[7];
  float inv = 1.0f / s;
  lg[tid] = e0 * inv;
  lg[tid + 256] = e1 * inv;
  __syncthreads();

  float acc = 0.0f;
#pragma unroll 4
  for (int t = 0; t < L; ++t) acc = fmaf(lg[t], base[(size_t)t * D + tid], acc);
  utt[(size_t)b * D + tid] = acc;
}

// ---------------------------------------------------------------------------
// Kernel E: sentence GRU (T=1, h0=0) -> dialog_vec = (1-z)*n
// ---------------------------------------------------------------------------
__global__ __launch_bounds__(256) void sent_kernel(
    const float* __restrict__ utt, const float* __restrict__ Wih,
    const float* __restrict__ bih, const float* __restrict__ bhh,
    float* __restrict__ out) {
  __shared__ float u[D];
  const int d = threadIdx.x, b = blockIdx.x;
  u[d] = utt[(size_t)b * D + d];
  __syncthreads();

  const float* wr = Wih + (size_t)d * D;
  const float* wz = Wih + (size_t)(D + d) * D;
  const float* wn = Wih + (size_t)(2 * D + d) * D;
  float ar = 0.0f, az = 0.0f, an = 0.0f;
  for (int k = 0; k < D; k += 4) {
    float4 vr = *(const float4*)(wr + k);
    float4 vz = *(const float4*)(wz + k);
    float4 vn = *(const float4*)(wn + k);
    float u0 = u[k], u1 = u[k + 1], u2 = u[k + 2], u3 = u[k + 3];
    ar += vr.x * u0 + vr.y * u1 + vr.z * u2 + vr.w * u3;
    az += vz.x * u0 + vz.y * u1 + vz.z * u2 + vz.w * u3;
    an += vn.x * u0 + vn.y * u1 + vn.z * u2 + vn.w * u3;
  }
  float xr = ar + bih[d];
  float xz = az + bih[D + d];
  float xn = an + bih[2 * D + d];
  float r = sigm(xr + bhh[d]);
  float z = sigm(xz + bhh[D + d]);
  float n = tanh_f(xn + r * bhh[2 * D + d]);
  out[(size_t)b * D + d] = (1.0f - z) * n;
}

// ---------------------------------------------------------------------------
extern "C" void kernel_launch(void* const* d_in, const int* in_sizes, int n_in,
                              void* d_out, int out_size, void* d_ws, size_t ws_size,
                              hipStream_t stream) {
  const int* tokens    = (const int*)d_in[0];
  const float* embed   = (const float*)d_in[1];
  const float* wg_Wih  = (const float*)d_in[2];
  const float* wg_Whh  = (const float*)d_in[3];
  const float* wg_bih  = (const float*)d_in[4];
  const float* wg_bhh  = (const float*)d_in[5];
  const float* ua_w    = (const float*)d_in[6];
  // d_in[7] ua_b: softmax shift-invariant -> unused
  const float* sg_Wih  = (const float*)d_in[8];
  // d_in[9] sg_Whh: h0 == 0 -> unused
  const float* sg_bih  = (const float*)d_in[10];
  const float* sg_bhh  = (const float*)d_in[11];
  // d_in[12..13] da_w/da_b: softmax over T=1 -> unused
  float* out = (float*)d_out;

  char* ws = (char*)d_ws;
  float* gx  = (float*)ws;                                     // 96 MB
  float* wo  = (float*)(ws + (size_t)NUTT * L * G * 4);        // 32 MB
  float* utt = (float*)(ws + (size_t)NUTT * L * G * 4
                           + (size_t)NUTT * L * D * 4);        // 64 KB

  dim3 gB(512, 6);
  gx_gemm<<<gB, 256, 0, stream>>>(tokens, embed, wg_Wih, wg_bih, gx);
  gru_scan_word<<<NUTT, 512, 0, stream>>>(gx, wg_Whh, wg_bhh, wo);
  attn_pool_word<<<NUTT, 256, 0, stream>>>(wo, ua_w, utt);
  sent_kernel<<<NUTT, 256, 0, stream>>>(utt, sg_Wih, sg_bih, sg_bhh, out);
}